// Round 5
// baseline (347.458 us; speedup 1.0000x reference)
//
#include <hip/hip_runtime.h>
#include <math.h>

#define BB 2
#define LL 1536
#define DD 768
#define HH 12
#define DKK 64
#define ZNEG -5.0e8f   // NEG/2: reference masks scores to -1e9, then z = scores/2

typedef __attribute__((ext_vector_type(8))) short bf16x8;           // 8 bf16 (4 VGPRs)
typedef __attribute__((ext_vector_type(8))) unsigned short u16x8;
typedef __attribute__((ext_vector_type(4))) float f32x4;

__device__ __forceinline__ unsigned short f32_to_bf16_rn(float x) {
    unsigned int u = __float_as_uint(x);
    u += 0x7fffu + ((u >> 16) & 1u);          // round-to-nearest-even
    return (unsigned short)(u >> 16);
}
__device__ __forceinline__ float bf16u_to_f32(unsigned short h) {
    return __uint_as_float(((unsigned int)h) << 16);
}

// Split 8 consecutive f32 into bf16 hi/lo halves; store 16 B of each to LDS.
__device__ __forceinline__ void split8(const float* __restrict__ gsrc,
                                       unsigned short* __restrict__ hdst,
                                       unsigned short* __restrict__ ldst) {
    float4 v0 = *reinterpret_cast<const float4*>(gsrc);
    float4 v1 = *reinterpret_cast<const float4*>(gsrc + 4);
    float f[8] = {v0.x, v0.y, v0.z, v0.w, v1.x, v1.y, v1.z, v1.w};
    u16x8 hi, lo;
    #pragma unroll
    for (int i = 0; i < 8; ++i) {
        unsigned short h = f32_to_bf16_rn(f[i]);
        float r = f[i] - bf16u_to_f32(h);
        hi[i] = h;
        lo[i] = f32_to_bf16_rn(r);
    }
    *reinterpret_cast<u16x8*>(hdst) = hi;
    *reinterpret_cast<u16x8*>(ldst) = lo;
}

// ---------------------------------------------------------------------------
// Kernel 1: fused Q/K projection via split-bf16 MFMA.
// out[m,n] = sum_k X[m,k]*W[n,k] + bias[n];  M=3072, N=768, K=768.
// Epilogue stores PRE-SPLIT bf16 hi/lo arrays [B,L,D] row-major so that K2
// can load MFMA fragments directly from global (k-contiguous 16B per lane).
// ---------------------------------------------------------------------------
__global__ __launch_bounds__(256) void proj_mfma(
    const float* __restrict__ Xq, const float* __restrict__ Xk,
    const float* __restrict__ Wq, const float* __restrict__ Wk,
    const float* __restrict__ bq, const float* __restrict__ bk,
    unsigned short* __restrict__ Qh, unsigned short* __restrict__ Ql,
    unsigned short* __restrict__ Kh, unsigned short* __restrict__ Kl)
{
    const float* X    = blockIdx.z ? Xk : Xq;
    const float* W    = blockIdx.z ? Wk : Wq;
    const float* bias = blockIdx.z ? bk : bq;
    unsigned short* Oh = blockIdx.z ? Kh : Qh;
    unsigned short* Ol = blockIdx.z ? Kl : Ql;

    __shared__ alignas(16) unsigned short Ah[8 * 64 * 8];  // 8 KB
    __shared__ alignas(16) unsigned short Al[8 * 64 * 8];  // 8 KB
    __shared__ alignas(16) unsigned short Bh[4 * 64 * 8];  // 4 KB
    __shared__ alignas(16) unsigned short Bl[4 * 64 * 8];  // 4 KB

    const int tid  = threadIdx.x;
    const int lane = tid & 63;
    const int w    = tid >> 6;
    const int wm   = w & 1;          // 2 m-halves of 64 rows
    const int wn   = w >> 1;         // 2 n-halves of 32 cols
    const int m0   = blockIdx.y * 128;
    const int n0   = blockIdx.x * 64;

    f32x4 acc[4][2] = {};

    for (int k0 = 0; k0 < DD; k0 += 32) {
        #pragma unroll
        for (int i = 0; i < 2; ++i) {
            const int c = tid + (i << 8);
            const int m = c >> 2, g = c & 3;
            const int slot = ((m >> 4) * 64 + (m & 15) + (g << 4)) * 8;
            split8(X + (size_t)(m0 + m) * DD + k0 + g * 8, Ah + slot, Al + slot);
        }
        {
            const int n = tid >> 2, g = tid & 3;
            const int slot = ((n >> 4) * 64 + (n & 15) + (g << 4)) * 8;
            split8(W + (size_t)(n0 + n) * DD + k0 + g * 8, Bh + slot, Bl + slot);
        }
        __syncthreads();

        bf16x8 aH[4], aL[4], bH[2], bL[2];
        #pragma unroll
        for (int fm = 0; fm < 4; ++fm) {
            const int f = wm * 4 + fm;
            aH[fm] = *reinterpret_cast<const bf16x8*>(Ah + (f * 64 + lane) * 8);
            aL[fm] = *reinterpret_cast<const bf16x8*>(Al + (f * 64 + lane) * 8);
        }
        #pragma unroll
        for (int fn = 0; fn < 2; ++fn) {
            const int f = wn * 2 + fn;
            bH[fn] = *reinterpret_cast<const bf16x8*>(Bh + (f * 64 + lane) * 8);
            bL[fn] = *reinterpret_cast<const bf16x8*>(Bl + (f * 64 + lane) * 8);
        }
        #pragma unroll
        for (int fm = 0; fm < 4; ++fm)
            #pragma unroll
            for (int fn = 0; fn < 2; ++fn) {
                acc[fm][fn] = __builtin_amdgcn_mfma_f32_16x16x32_bf16(aH[fm], bH[fn], acc[fm][fn], 0, 0, 0);
                acc[fm][fn] = __builtin_amdgcn_mfma_f32_16x16x32_bf16(aH[fm], bL[fn], acc[fm][fn], 0, 0, 0);
                acc[fm][fn] = __builtin_amdgcn_mfma_f32_16x16x32_bf16(aL[fm], bH[fn], acc[fm][fn], 0, 0, 0);
            }
        __syncthreads();
    }

    // ---- epilogue: C/D layout col=lane&15, row=(lane>>4)*4+reg [m89] ----
    const int r0 = (lane >> 4) << 2;
    const int cl = lane & 15;
    #pragma unroll
    for (int fn = 0; fn < 2; ++fn) {
        const int col = n0 + wn * 32 + fn * 16 + cl;
        const float bv = bias[col];
        #pragma unroll
        for (int fm = 0; fm < 4; ++fm) {
            const int row = m0 + wm * 64 + fm * 16 + r0;
            #pragma unroll
            for (int r = 0; r < 4; ++r) {
                const float v = acc[fm][fn][r] + bv;
                const unsigned short h16 = f32_to_bf16_rn(v);
                const float res = v - bf16u_to_f32(h16);
                const size_t o = (size_t)(row + r) * DD + col;
                Oh[o] = h16;
                Ol[o] = f32_to_bf16_rn(res);
            }
        }
    }
}

// ---------------------------------------------------------------------------
// Kernel 2: scores z = (q.k)/16, masked keys -> ZNEG, split-bf16 MFMA with
// DIRECT global->register fragment loads (no LDS, no barriers, no conversion).
// Fragment address derivation verified by inverting the validated round-4
// LDS slot formula: lane l, frag (fm,qq) of A reads 16B at
//   (b*LL + q0 + (wm*4+fm)*16 + (l&15))*DD + h*64 + qq*32 + (l>>4)*8.
// Per (b,h): M=N=1536, K=64. Tile 128x64, 4 waves x (64x32).
// ---------------------------------------------------------------------------
__global__ __launch_bounds__(256) void scores_mfma(
    const unsigned short* __restrict__ Qh, const unsigned short* __restrict__ Ql,
    const unsigned short* __restrict__ Kh, const unsigned short* __restrict__ Kl,
    const int* __restrict__ mask, float* __restrict__ S)
{
    const int bh = blockIdx.z;
    const int b  = bh / HH;
    const int h  = bh - b * HH;
    const int q0 = blockIdx.y * 128;
    const int n0 = blockIdx.x * 64;

    const int tid  = threadIdx.x;
    const int lane = tid & 63;
    const int w    = tid >> 6;
    const int wm   = w & 1;
    const int wn   = w >> 1;
    const int lr   = lane & 15;    // row within fragment
    const int lk   = lane >> 4;    // k-subgroup (8 bf16 each)

    const size_t abase = (size_t)(b * LL + q0 + wm * 64 + lr) * DD + h * DKK + lk * 8;
    const size_t bbase = (size_t)(b * LL + n0 + wn * 32 + lr) * DD + h * DKK + lk * 8;

    f32x4 acc[4][2] = {};

    #pragma unroll
    for (int qq = 0; qq < 2; ++qq) {
        bf16x8 aH[4], aL[4], bH[2], bL[2];
        #pragma unroll
        for (int fm = 0; fm < 4; ++fm) {
            const size_t o = abase + (size_t)fm * 16 * DD + qq * 32;
            aH[fm] = *reinterpret_cast<const bf16x8*>(Qh + o);
            aL[fm] = *reinterpret_cast<const bf16x8*>(Ql + o);
        }
        #pragma unroll
        for (int fn = 0; fn < 2; ++fn) {
            const size_t o = bbase + (size_t)fn * 16 * DD + qq * 32;
            bH[fn] = *reinterpret_cast<const bf16x8*>(Kh + o);
            bL[fn] = *reinterpret_cast<const bf16x8*>(Kl + o);
        }
        #pragma unroll
        for (int fm = 0; fm < 4; ++fm)
            #pragma unroll
            for (int fn = 0; fn < 2; ++fn) {
                acc[fm][fn] = __builtin_amdgcn_mfma_f32_16x16x32_bf16(aH[fm], bH[fn], acc[fm][fn], 0, 0, 0);
                acc[fm][fn] = __builtin_amdgcn_mfma_f32_16x16x32_bf16(aH[fm], bL[fn], acc[fm][fn], 0, 0, 0);
                acc[fm][fn] = __builtin_amdgcn_mfma_f32_16x16x32_bf16(aL[fm], bH[fn], acc[fm][fn], 0, 0, 0);
            }
    }

    // ---- epilogue: scale 1/16, mask, store f32 ----
    const int r0 = (lane >> 4) << 2;
    const int cl = lane & 15;
    #pragma unroll
    for (int fn = 0; fn < 2; ++fn) {
        const int col = n0 + wn * 32 + fn * 16 + cl;
        const int mk  = mask[b * LL + col];
        #pragma unroll
        for (int fm = 0; fm < 4; ++fm) {
            const int row = q0 + wm * 64 + fm * 16 + r0;
            const size_t base = ((size_t)bh * LL + row) * LL + col;
            #pragma unroll
            for (int r = 0; r < 4; ++r) {
                const float v = acc[fm][fn][r] * 0.0625f;   // (qk/8)/2
                S[base + (size_t)r * LL] = mk ? v : ZNEG;
            }
        }
    }
}

// ---------------------------------------------------------------------------
// Kernel 3: entmax-1.5, wave-per-head with ACTIVE-SET bisection.
// After the max-shift, tau* in [-1,0], so only elements z > -1 ever contribute
// to f(tau) = sum max(z-tau,0)^2. Typically ~50/1536 are active. Per head:
// count + wave-prefix-scan actives, compact to LDS, bisect over <=2 register
// values/lane (ntot<=128); generic LDS-strided fallback keeps correctness for
// any ntot. Final p uses the full 24 register values as before.
// ---------------------------------------------------------------------------
__device__ __forceinline__ float waveReduceSum(float v) {
    #pragma unroll
    for (int off = 32; off > 0; off >>= 1) v += __shfl_xor(v, off, 64);
    return v;
}
__device__ __forceinline__ float waveReduceMax(float v) {
    #pragma unroll
    for (int off = 32; off > 0; off >>= 1) v = fmaxf(v, __shfl_xor(v, off, 64));
    return v;
}

__global__ __launch_bounds__(256) void entmax_sum(
    const float* __restrict__ S, float* __restrict__ out)
{
    const int bq = blockIdx.x;          // b*LL + q
    const int b  = bq / LL;
    const int q  = bq - b * LL;
    const int tid = threadIdx.x;
    const int w  = tid >> 6;            // wave 0..3
    const int l  = tid & 63;            // lane 0..63

    __shared__ float buf[4][LL];        // compaction scratch, then head-partials

    float acc[24];
    #pragma unroll
    for (int i = 0; i < 24; ++i) acc[i] = 0.0f;

    #pragma unroll
    for (int hh = 0; hh < 3; ++hh) {
        const int h = w + (hh << 2);
        const float* row = S + ((size_t)(b * HH + h) * LL + q) * LL + l * 24;

        float z[24];
        #pragma unroll
        for (int i = 0; i < 24; i += 4) {
            float4 v = *reinterpret_cast<const float4*>(row + i);
            z[i] = v.x; z[i + 1] = v.y; z[i + 2] = v.z; z[i + 3] = v.w;
        }

        // ---- wave max + shift ----
        float m = z[0];
        #pragma unroll
        for (int i = 1; i < 24; ++i) m = fmaxf(m, z[i]);
        m = waveReduceMax(m);
        #pragma unroll
        for (int i = 0; i < 24; ++i) z[i] -= m;

        // ---- count actives (z > -1) and wave-exclusive prefix ----
        int nloc = 0;
        #pragma unroll
        for (int i = 0; i < 24; ++i) nloc += (z[i] > -1.0f) ? 1 : 0;
        int incl = nloc;
        #pragma unroll
        for (int off = 1; off <= 32; off <<= 1) {
            int t = __shfl_up(incl, off, 64);
            if (l >= off) incl += t;
        }
        const int ntot = __shfl(incl, 63, 64);

        // ---- compact actives into this wave's LDS row ----
        int p = incl - nloc;
        #pragma unroll
        for (int i = 0; i < 24; ++i)
            if (z[i] > -1.0f) buf[w][p++] = z[i];
        __syncthreads();

        // ---- bisection for tau in [-1, 0] over actives only ----
        float tlo = -1.0f, thi = 0.0f;
        if (ntot <= 128) {
            float x0 = (l < ntot)      ? buf[w][l]      : -2.0f;
            float x1 = (l + 64 < ntot) ? buf[w][l + 64] : -2.0f;
            for (int it = 0; it < 16; ++it) {
                const float tau = 0.5f * (tlo + thi);
                const float t0 = fmaxf(x0 - tau, 0.0f);
                const float t1 = fmaxf(x1 - tau, 0.0f);
                float s = fmaf(t0, t0, t1 * t1);
                s = waveReduceSum(s);
                if (s >= 1.0f) tlo = tau; else thi = tau;
            }
        } else {
            for (int it = 0; it < 16; ++it) {
                const float tau = 0.5f * (tlo + thi);
                float s = 0.0f;
                for (int j = l; j < ntot; j += 64) {
                    const float t = fmaxf(buf[w][j] - tau, 0.0f);
                    s = fmaf(t, t, s);
                }
                s = waveReduceSum(s);
                if (s >= 1.0f) tlo = tau; else thi = tau;
            }
        }
        __syncthreads();   // frees buf for next head / final join

        const float tau = 0.5f * (tlo + thi);
        #pragma unroll
        for (int i = 0; i < 24; ++i) {
            const float t = fmaxf(z[i] - tau, 0.0f);
            acc[i] = fmaf(t, t, acc[i]);
        }
    }

    // ---- join the 4 waves' head-partials ----
    #pragma unroll
    for (int i = 0; i < 24; ++i) buf[w][l * 24 + i] = acc[i];
    __syncthreads();

    float* orow = out + (size_t)bq * LL;
    #pragma unroll
    for (int i = 0; i < 6; ++i) {
        const int c = tid + (i << 8);
        orow[c] = (buf[0][c] + buf[1][c] + buf[2][c] + buf[3][c]) * (1.0f / 12.0f);
    }
}

// ---------------------------------------------------------------------------
extern "C" void kernel_launch(void* const* d_in, const int* in_sizes, int n_in,
                              void* d_out, int out_size, void* d_ws, size_t ws_size,
                              hipStream_t stream) {
    (void)in_sizes; (void)n_in; (void)out_size; (void)ws_size;
    const float* query = (const float*)d_in[0];
    const float* key   = (const float*)d_in[1];
    const int*   mask  = (const int*)d_in[2];
    const float* wq_w  = (const float*)d_in[3];
    const float* wq_b  = (const float*)d_in[4];
    const float* wk_w  = (const float*)d_in[5];
    const float* wk_b  = (const float*)d_in[6];
    float* out = (float*)d_out;

    const size_t NE = (size_t)BB * LL * DD;         // 2359296 elems
    unsigned short* Qh = (unsigned short*)d_ws;     // 4.7 MB each
    unsigned short* Ql = Qh + NE;
    unsigned short* Kh = Ql + NE;
    unsigned short* Kl = Kh + NE;
    float* S = (float*)(Kl + NE);                   // [B,H,L,L] 226.5 MB

    // K1: projections -> pre-split bf16 hi/lo (z dim: 0 = Q, 1 = K)
    proj_mfma<<<dim3(DD / 64, (BB * LL) / 128, 2), 256, 0, stream>>>(
        query, key, wq_w, wk_w, wq_b, wk_b, Qh, Ql, Kh, Kl);

    // K2: masked, pre-scaled scores (direct fragment loads)
    scores_mfma<<<dim3(LL / 64, LL / 128, BB * HH), 256, 0, stream>>>(
        Qh, Ql, Kh, Kl, mask, S);

    // K3: entmax + head average (active-set bisection)
    entmax_sum<<<BB * LL, 256, 0, stream>>>(S, out);
}

// Round 6
// 244.146 us; speedup vs baseline: 1.4232x; 1.4232x over previous
//
#include <hip/hip_runtime.h>
#include <math.h>

#define BB 2
#define LL 1536
#define DD 768
#define HH 12
#define DKK 64
#define ZNEG -5.0e8f   // NEG/2: reference masks scores to -1e9, then z = scores/2

typedef __attribute__((ext_vector_type(8))) short bf16x8;           // 8 bf16 (4 VGPRs)
typedef __attribute__((ext_vector_type(8))) unsigned short u16x8;
typedef __attribute__((ext_vector_type(4))) float f32x4;

__device__ __forceinline__ unsigned short f32_to_bf16_rn(float x) {
    unsigned int u = __float_as_uint(x);
    u += 0x7fffu + ((u >> 16) & 1u);          // round-to-nearest-even
    return (unsigned short)(u >> 16);
}
__device__ __forceinline__ float bf16u_to_f32(unsigned short h) {
    return __uint_as_float(((unsigned int)h) << 16);
}

// Split 8 consecutive f32 into bf16 hi/lo halves; store 16 B of each to LDS.
__device__ __forceinline__ void split8(const float* __restrict__ gsrc,
                                       unsigned short* __restrict__ hdst,
                                       unsigned short* __restrict__ ldst) {
    float4 v0 = *reinterpret_cast<const float4*>(gsrc);
    float4 v1 = *reinterpret_cast<const float4*>(gsrc + 4);
    float f[8] = {v0.x, v0.y, v0.z, v0.w, v1.x, v1.y, v1.z, v1.w};
    u16x8 hi, lo;
    #pragma unroll
    for (int i = 0; i < 8; ++i) {
        unsigned short h = f32_to_bf16_rn(f[i]);
        float r = f[i] - bf16u_to_f32(h);
        hi[i] = h;
        lo[i] = f32_to_bf16_rn(r);
    }
    *reinterpret_cast<u16x8*>(hdst) = hi;
    *reinterpret_cast<u16x8*>(ldst) = lo;
}

// ---------------------------------------------------------------------------
// Kernel 1: fused Q/K projection via split-bf16 MFMA.
// out[m,n] = sum_k X[m,k]*W[n,k] + bias[n];  M=3072, N=768, K=768.
// Epilogue stores PRE-SPLIT bf16 hi/lo arrays [B,L,D] row-major; K2 stages
// them into LDS with plain coalesced copies (no conversion in K2).
// ---------------------------------------------------------------------------
__global__ __launch_bounds__(256) void proj_mfma(
    const float* __restrict__ Xq, const float* __restrict__ Xk,
    const float* __restrict__ Wq, const float* __restrict__ Wk,
    const float* __restrict__ bq, const float* __restrict__ bk,
    unsigned short* __restrict__ Qh, unsigned short* __restrict__ Ql,
    unsigned short* __restrict__ Kh, unsigned short* __restrict__ Kl)
{
    const float* X    = blockIdx.z ? Xk : Xq;
    const float* W    = blockIdx.z ? Wk : Wq;
    const float* bias = blockIdx.z ? bk : bq;
    unsigned short* Oh = blockIdx.z ? Kh : Qh;
    unsigned short* Ol = blockIdx.z ? Kl : Ql;

    __shared__ alignas(16) unsigned short Ah[8 * 64 * 8];  // 8 KB
    __shared__ alignas(16) unsigned short Al[8 * 64 * 8];  // 8 KB
    __shared__ alignas(16) unsigned short Bh[4 * 64 * 8];  // 4 KB
    __shared__ alignas(16) unsigned short Bl[4 * 64 * 8];  // 4 KB

    const int tid  = threadIdx.x;
    const int lane = tid & 63;
    const int w    = tid >> 6;
    const int wm   = w & 1;          // 2 m-halves of 64 rows
    const int wn   = w >> 1;         // 2 n-halves of 32 cols
    const int m0   = blockIdx.y * 128;
    const int n0   = blockIdx.x * 64;

    f32x4 acc[4][2] = {};

    for (int k0 = 0; k0 < DD; k0 += 32) {
        #pragma unroll
        for (int i = 0; i < 2; ++i) {
            const int c = tid + (i << 8);
            const int m = c >> 2, g = c & 3;
            const int slot = ((m >> 4) * 64 + (m & 15) + (g << 4)) * 8;
            split8(X + (size_t)(m0 + m) * DD + k0 + g * 8, Ah + slot, Al + slot);
        }
        {
            const int n = tid >> 2, g = tid & 3;
            const int slot = ((n >> 4) * 64 + (n & 15) + (g << 4)) * 8;
            split8(W + (size_t)(n0 + n) * DD + k0 + g * 8, Bh + slot, Bl + slot);
        }
        __syncthreads();

        bf16x8 aH[4], aL[4], bH[2], bL[2];
        #pragma unroll
        for (int fm = 0; fm < 4; ++fm) {
            const int f = wm * 4 + fm;
            aH[fm] = *reinterpret_cast<const bf16x8*>(Ah + (f * 64 + lane) * 8);
            aL[fm] = *reinterpret_cast<const bf16x8*>(Al + (f * 64 + lane) * 8);
        }
        #pragma unroll
        for (int fn = 0; fn < 2; ++fn) {
            const int f = wn * 2 + fn;
            bH[fn] = *reinterpret_cast<const bf16x8*>(Bh + (f * 64 + lane) * 8);
            bL[fn] = *reinterpret_cast<const bf16x8*>(Bl + (f * 64 + lane) * 8);
        }
        #pragma unroll
        for (int fm = 0; fm < 4; ++fm)
            #pragma unroll
            for (int fn = 0; fn < 2; ++fn) {
                acc[fm][fn] = __builtin_amdgcn_mfma_f32_16x16x32_bf16(aH[fm], bH[fn], acc[fm][fn], 0, 0, 0);
                acc[fm][fn] = __builtin_amdgcn_mfma_f32_16x16x32_bf16(aH[fm], bL[fn], acc[fm][fn], 0, 0, 0);
                acc[fm][fn] = __builtin_amdgcn_mfma_f32_16x16x32_bf16(aL[fm], bH[fn], acc[fm][fn], 0, 0, 0);
            }
        __syncthreads();
    }

    // ---- epilogue: C/D layout col=lane&15, row=(lane>>4)*4+reg [m89] ----
    const int r0 = (lane >> 4) << 2;
    const int cl = lane & 15;
    #pragma unroll
    for (int fn = 0; fn < 2; ++fn) {
        const int col = n0 + wn * 32 + fn * 16 + cl;
        const float bv = bias[col];
        #pragma unroll
        for (int fm = 0; fm < 4; ++fm) {
            const int row = m0 + wm * 64 + fm * 16 + r0;
            #pragma unroll
            for (int r = 0; r < 4; ++r) {
                const float v = acc[fm][fn][r] + bv;
                const unsigned short h16 = f32_to_bf16_rn(v);
                const float res = v - bf16u_to_f32(h16);
                const size_t o = (size_t)(row + r) * DD + col;
                Oh[o] = h16;
                Ol[o] = f32_to_bf16_rn(res);
            }
        }
    }
}

// ---------------------------------------------------------------------------
// Kernel 2: scores z = (q.k)/16, masked keys -> ZNEG, split-bf16 MFMA.
// Round-4 structure (coalesced LDS staging, verified slot/fragment formulas)
// but staging is now a PURE COPY of pre-split bf16 hi/lo (no conversion).
// Per (b,h): M=N=1536, K=64 (2 k-chunks of 32, staged once). Tile 128x64.
// ---------------------------------------------------------------------------
__global__ __launch_bounds__(256) void scores_mfma(
    const unsigned short* __restrict__ Qh, const unsigned short* __restrict__ Ql,
    const unsigned short* __restrict__ Kh, const unsigned short* __restrict__ Kl,
    const int* __restrict__ mask, float* __restrict__ S)
{
    const int bh = blockIdx.z;
    const int b  = bh / HH;
    const int h  = bh - b * HH;
    const int q0 = blockIdx.y * 128;
    const int n0 = blockIdx.x * 64;

    __shared__ alignas(16) unsigned short Ah[8 * 2 * 64 * 8];  // 16 KB
    __shared__ alignas(16) unsigned short Al[8 * 2 * 64 * 8];  // 16 KB
    __shared__ alignas(16) unsigned short Bh[4 * 2 * 64 * 8];  //  8 KB
    __shared__ alignas(16) unsigned short Bl[4 * 2 * 64 * 8];  //  8 KB

    const int tid  = threadIdx.x;
    const int lane = tid & 63;
    const int w    = tid >> 6;
    const int wm   = w & 1;
    const int wn   = w >> 1;

    // ---- stage A: 1024 16B chunks (m 0..127, c8 0..7), coalesced copy ----
    #pragma unroll
    for (int i = 0; i < 4; ++i) {
        const int c = tid + (i << 8);
        const int m = c >> 3, c8 = c & 7;
        const int qq = c8 >> 2, g = c8 & 3;
        const int slot = (((m >> 4) * 2 + qq) * 64 + (m & 15) + (g << 4)) * 8;
        const size_t o = (size_t)(b * LL + q0 + m) * DD + h * DKK + c8 * 8;
        *reinterpret_cast<u16x8*>(Ah + slot) = *reinterpret_cast<const u16x8*>(Qh + o);
        *reinterpret_cast<u16x8*>(Al + slot) = *reinterpret_cast<const u16x8*>(Ql + o);
    }
    // ---- stage B: 512 chunks (n 0..63, c8 0..7) ----
    #pragma unroll
    for (int i = 0; i < 2; ++i) {
        const int c = tid + (i << 8);
        const int n = c >> 3, c8 = c & 7;
        const int qq = c8 >> 2, g = c8 & 3;
        const int slot = (((n >> 4) * 2 + qq) * 64 + (n & 15) + (g << 4)) * 8;
        const size_t o = (size_t)(b * LL + n0 + n) * DD + h * DKK + c8 * 8;
        *reinterpret_cast<u16x8*>(Bh + slot) = *reinterpret_cast<const u16x8*>(Kh + o);
        *reinterpret_cast<u16x8*>(Bl + slot) = *reinterpret_cast<const u16x8*>(Kl + o);
    }
    __syncthreads();

    f32x4 acc[4][2] = {};
    #pragma unroll
    for (int qq = 0; qq < 2; ++qq) {
        bf16x8 aH[4], aL[4], bH[2], bL[2];
        #pragma unroll
        for (int fm = 0; fm < 4; ++fm) {
            const int f = (wm * 4 + fm) * 2 + qq;
            aH[fm] = *reinterpret_cast<const bf16x8*>(Ah + (f * 64 + lane) * 8);
            aL[fm] = *reinterpret_cast<const bf16x8*>(Al + (f * 64 + lane) * 8);
        }
        #pragma unroll
        for (int fn = 0; fn < 2; ++fn) {
            const int f = (wn * 2 + fn) * 2 + qq;
            bH[fn] = *reinterpret_cast<const bf16x8*>(Bh + (f * 64 + lane) * 8);
            bL[fn] = *reinterpret_cast<const bf16x8*>(Bl + (f * 64 + lane) * 8);
        }
        #pragma unroll
        for (int fm = 0; fm < 4; ++fm)
            #pragma unroll
            for (int fn = 0; fn < 2; ++fn) {
                acc[fm][fn] = __builtin_amdgcn_mfma_f32_16x16x32_bf16(aH[fm], bH[fn], acc[fm][fn], 0, 0, 0);
                acc[fm][fn] = __builtin_amdgcn_mfma_f32_16x16x32_bf16(aH[fm], bL[fn], acc[fm][fn], 0, 0, 0);
                acc[fm][fn] = __builtin_amdgcn_mfma_f32_16x16x32_bf16(aL[fm], bH[fn], acc[fm][fn], 0, 0, 0);
            }
    }

    // ---- epilogue: scale 1/16, mask, store f32 ----
    const int r0 = (lane >> 4) << 2;
    const int cl = lane & 15;
    #pragma unroll
    for (int fn = 0; fn < 2; ++fn) {
        const int col = n0 + wn * 32 + fn * 16 + cl;
        const int mk  = mask[b * LL + col];
        #pragma unroll
        for (int fm = 0; fm < 4; ++fm) {
            const int row = q0 + wm * 64 + fm * 16 + r0;
            const size_t base = ((size_t)bh * LL + row) * LL + col;
            #pragma unroll
            for (int r = 0; r < 4; ++r) {
                const float v = acc[fm][fn][r] * 0.0625f;   // (qk/8)/2
                S[base + (size_t)r * LL] = mk ? v : ZNEG;
            }
        }
    }
}

// ---------------------------------------------------------------------------
// Kernel 3: entmax-1.5, wave-per-head (round-4 verified structure, 13 iters).
// tau* is the unique root of f(tau) = sum max(z-tau,0)^2 = 1, tau* in [-1,0];
// 13 bisection steps -> |dtau| <= 6.1e-5 -> p error <= 1.3e-4 << 8.25e-4.
// All reductions are intra-wave shuffle butterflies (no barriers in the loop).
// ---------------------------------------------------------------------------
__device__ __forceinline__ float waveReduceSum(float v) {
    #pragma unroll
    for (int off = 32; off > 0; off >>= 1) v += __shfl_xor(v, off, 64);
    return v;
}
__device__ __forceinline__ float waveReduceMax(float v) {
    #pragma unroll
    for (int off = 32; off > 0; off >>= 1) v = fmaxf(v, __shfl_xor(v, off, 64));
    return v;
}

__global__ __launch_bounds__(256) void entmax_sum(
    const float* __restrict__ S, float* __restrict__ out)
{
    const int bq = blockIdx.x;          // b*LL + q
    const int b  = bq / LL;
    const int q  = bq - b * LL;
    const int tid = threadIdx.x;
    const int w  = tid >> 6;            // wave 0..3
    const int l  = tid & 63;            // lane 0..63

    __shared__ float buf[4][LL];        // per-wave head-partials, 24 KB

    float acc[24];
    #pragma unroll
    for (int i = 0; i < 24; ++i) acc[i] = 0.0f;

    #pragma unroll
    for (int hh = 0; hh < 3; ++hh) {
        const int h = w + (hh << 2);
        const float* row = S + ((size_t)(b * HH + h) * LL + q) * LL + l * 24;

        float z[24];
        #pragma unroll
        for (int i = 0; i < 24; i += 4) {
            float4 v = *reinterpret_cast<const float4*>(row + i);
            z[i] = v.x; z[i + 1] = v.y; z[i + 2] = v.z; z[i + 3] = v.w;
        }

        // ---- wave max ----
        float m = z[0];
        #pragma unroll
        for (int i = 1; i < 24; ++i) m = fmaxf(m, z[i]);
        m = waveReduceMax(m);

        #pragma unroll
        for (int i = 0; i < 24; ++i) z[i] -= m;

        // ---- bisection for tau in [-1, 0] ----
        float lo = -1.0f, hi_ = 0.0f;
        for (int it = 0; it < 13; ++it) {
            const float tau = 0.5f * (lo + hi_);
            float s = 0.0f;
            #pragma unroll
            for (int i = 0; i < 24; ++i) {
                const float t = fmaxf(z[i] - tau, 0.0f);
                s = fmaf(t, t, s);
            }
            s = waveReduceSum(s);
            if (s >= 1.0f) lo = tau; else hi_ = tau;
        }
        const float tau = 0.5f * (lo + hi_);

        #pragma unroll
        for (int i = 0; i < 24; ++i) {
            const float t = fmaxf(z[i] - tau, 0.0f);
            acc[i] = fmaf(t, t, acc[i]);
        }
    }

    // ---- join the 4 waves' head-partials ----
    #pragma unroll
    for (int i = 0; i < 24; ++i) buf[w][l * 24 + i] = acc[i];
    __syncthreads();

    float* orow = out + (size_t)bq * LL;
    #pragma unroll
    for (int i = 0; i < 6; ++i) {
        const int c = tid + (i << 8);
        orow[c] = (buf[0][c] + buf[1][c] + buf[2][c] + buf[3][c]) * (1.0f / 12.0f);
    }
}

// ---------------------------------------------------------------------------
extern "C" void kernel_launch(void* const* d_in, const int* in_sizes, int n_in,
                              void* d_out, int out_size, void* d_ws, size_t ws_size,
                              hipStream_t stream) {
    (void)in_sizes; (void)n_in; (void)out_size; (void)ws_size;
    const float* query = (const float*)d_in[0];
    const float* key   = (const float*)d_in[1];
    const int*   mask  = (const int*)d_in[2];
    const float* wq_w  = (const float*)d_in[3];
    const float* wq_b  = (const float*)d_in[4];
    const float* wk_w  = (const float*)d_in[5];
    const float* wk_b  = (const float*)d_in[6];
    float* out = (float*)d_out;

    const size_t NE = (size_t)BB * LL * DD;         // 2359296 elems
    unsigned short* Qh = (unsigned short*)d_ws;     // 4.7 MB each
    unsigned short* Ql = Qh + NE;
    unsigned short* Kh = Ql + NE;
    unsigned short* Kl = Kh + NE;
    float* S = (float*)(Kl + NE);                   // [B,H,L,L] 226.5 MB

    // K1: projections -> pre-split bf16 hi/lo (z dim: 0 = Q, 1 = K)
    proj_mfma<<<dim3(DD / 64, (BB * LL) / 128, 2), 256, 0, stream>>>(
        query, key, wq_w, wk_w, wq_b, wk_b, Qh, Ql, Kh, Kl);

    // K2: masked, pre-scaled scores (coalesced copy staging, no conversion)
    scores_mfma<<<dim3(LL / 64, LL / 128, BB * HH), 256, 0, stream>>>(
        Qh, Ql, Kh, Kl, mask, S);

    // K3: entmax + head average (13-iter bisection)
    entmax_sum<<<BB * LL, 256, 0, stream>>>(S, out);
}

// Round 7
// 231.165 us; speedup vs baseline: 1.5031x; 1.0562x over previous
//
#include <hip/hip_runtime.h>
#include <math.h>

#define BB 2
#define LL 1536
#define DD 768
#define HH 12
#define DKK 64
#define ZNEG -5.0e8f   // NEG/2: reference masks scores to -1e9, then z = scores/2

typedef __attribute__((ext_vector_type(8))) short bf16x8;           // 8 bf16 (4 VGPRs)
typedef __attribute__((ext_vector_type(8))) unsigned short u16x8;
typedef __attribute__((ext_vector_type(4))) float f32x4;

__device__ __forceinline__ unsigned short f32_to_bf16_rn(float x) {
    unsigned int u = __float_as_uint(x);
    u += 0x7fffu + ((u >> 16) & 1u);          // round-to-nearest-even
    return (unsigned short)(u >> 16);
}
__device__ __forceinline__ float bf16u_to_f32(unsigned short h) {
    return __uint_as_float(((unsigned int)h) << 16);
}

// Split 8 consecutive f32 into bf16 hi/lo halves; store 16 B of each to LDS.
__device__ __forceinline__ void split8(const float* __restrict__ gsrc,
                                       unsigned short* __restrict__ hdst,
                                       unsigned short* __restrict__ ldst) {
    float4 v0 = *reinterpret_cast<const float4*>(gsrc);
    float4 v1 = *reinterpret_cast<const float4*>(gsrc + 4);
    float f[8] = {v0.x, v0.y, v0.z, v0.w, v1.x, v1.y, v1.z, v1.w};
    u16x8 hi, lo;
    #pragma unroll
    for (int i = 0; i < 8; ++i) {
        unsigned short h = f32_to_bf16_rn(f[i]);
        float r = f[i] - bf16u_to_f32(h);
        hi[i] = h;
        lo[i] = f32_to_bf16_rn(r);
    }
    *reinterpret_cast<u16x8*>(hdst) = hi;
    *reinterpret_cast<u16x8*>(ldst) = lo;
}

// ---------------------------------------------------------------------------
// Kernel 1: fused Q/K projection via split-bf16 MFMA (round-6, verified).
// out[m,n] = sum_k X[m,k]*W[n,k] + bias[n];  M=3072, N=768, K=768.
// Epilogue stores PRE-SPLIT bf16 hi/lo arrays [B,L,D] row-major.
// ---------------------------------------------------------------------------
__global__ __launch_bounds__(256) void proj_mfma(
    const float* __restrict__ Xq, const float* __restrict__ Xk,
    const float* __restrict__ Wq, const float* __restrict__ Wk,
    const float* __restrict__ bq, const float* __restrict__ bk,
    unsigned short* __restrict__ Qh, unsigned short* __restrict__ Ql,
    unsigned short* __restrict__ Kh, unsigned short* __restrict__ Kl)
{
    const float* X    = blockIdx.z ? Xk : Xq;
    const float* W    = blockIdx.z ? Wk : Wq;
    const float* bias = blockIdx.z ? bk : bq;
    unsigned short* Oh = blockIdx.z ? Kh : Qh;
    unsigned short* Ol = blockIdx.z ? Kl : Ql;

    __shared__ alignas(16) unsigned short Ah[8 * 64 * 8];  // 8 KB
    __shared__ alignas(16) unsigned short Al[8 * 64 * 8];  // 8 KB
    __shared__ alignas(16) unsigned short Bh[4 * 64 * 8];  // 4 KB
    __shared__ alignas(16) unsigned short Bl[4 * 64 * 8];  // 4 KB

    const int tid  = threadIdx.x;
    const int lane = tid & 63;
    const int w    = tid >> 6;
    const int wm   = w & 1;          // 2 m-halves of 64 rows
    const int wn   = w >> 1;         // 2 n-halves of 32 cols
    const int m0   = blockIdx.y * 128;
    const int n0   = blockIdx.x * 64;

    f32x4 acc[4][2] = {};

    for (int k0 = 0; k0 < DD; k0 += 32) {
        #pragma unroll
        for (int i = 0; i < 2; ++i) {
            const int c = tid + (i << 8);
            const int m = c >> 2, g = c & 3;
            const int slot = ((m >> 4) * 64 + (m & 15) + (g << 4)) * 8;
            split8(X + (size_t)(m0 + m) * DD + k0 + g * 8, Ah + slot, Al + slot);
        }
        {
            const int n = tid >> 2, g = tid & 3;
            const int slot = ((n >> 4) * 64 + (n & 15) + (g << 4)) * 8;
            split8(W + (size_t)(n0 + n) * DD + k0 + g * 8, Bh + slot, Bl + slot);
        }
        __syncthreads();

        bf16x8 aH[4], aL[4], bH[2], bL[2];
        #pragma unroll
        for (int fm = 0; fm < 4; ++fm) {
            const int f = wm * 4 + fm;
            aH[fm] = *reinterpret_cast<const bf16x8*>(Ah + (f * 64 + lane) * 8);
            aL[fm] = *reinterpret_cast<const bf16x8*>(Al + (f * 64 + lane) * 8);
        }
        #pragma unroll
        for (int fn = 0; fn < 2; ++fn) {
            const int f = wn * 2 + fn;
            bH[fn] = *reinterpret_cast<const bf16x8*>(Bh + (f * 64 + lane) * 8);
            bL[fn] = *reinterpret_cast<const bf16x8*>(Bl + (f * 64 + lane) * 8);
        }
        #pragma unroll
        for (int fm = 0; fm < 4; ++fm)
            #pragma unroll
            for (int fn = 0; fn < 2; ++fn) {
                acc[fm][fn] = __builtin_amdgcn_mfma_f32_16x16x32_bf16(aH[fm], bH[fn], acc[fm][fn], 0, 0, 0);
                acc[fm][fn] = __builtin_amdgcn_mfma_f32_16x16x32_bf16(aH[fm], bL[fn], acc[fm][fn], 0, 0, 0);
                acc[fm][fn] = __builtin_amdgcn_mfma_f32_16x16x32_bf16(aL[fm], bH[fn], acc[fm][fn], 0, 0, 0);
            }
        __syncthreads();
    }

    // ---- epilogue: C/D layout col=lane&15, row=(lane>>4)*4+reg [m89] ----
    const int r0 = (lane >> 4) << 2;
    const int cl = lane & 15;
    #pragma unroll
    for (int fn = 0; fn < 2; ++fn) {
        const int col = n0 + wn * 32 + fn * 16 + cl;
        const float bv = bias[col];
        #pragma unroll
        for (int fm = 0; fm < 4; ++fm) {
            const int row = m0 + wm * 64 + fm * 16 + r0;
            #pragma unroll
            for (int r = 0; r < 4; ++r) {
                const float v = acc[fm][fn][r] + bv;
                const unsigned short h16 = f32_to_bf16_rn(v);
                const float res = v - bf16u_to_f32(h16);
                const size_t o = (size_t)(row + r) * DD + col;
                Oh[o] = h16;
                Ol[o] = f32_to_bf16_rn(res);
            }
        }
    }
}

// ---------------------------------------------------------------------------
// Kernel 2: scores z = (q.k)/16, masked keys -> ZNEG, split-bf16 MFMA
// (round-6 verified: coalesced pure-copy staging of pre-split hi/lo).
// Per (b,h): M=N=1536, K=64 (2 k-chunks of 32, staged once). Tile 128x64.
// ---------------------------------------------------------------------------
__global__ __launch_bounds__(256) void scores_mfma(
    const unsigned short* __restrict__ Qh, const unsigned short* __restrict__ Ql,
    const unsigned short* __restrict__ Kh, const unsigned short* __restrict__ Kl,
    const int* __restrict__ mask, float* __restrict__ S)
{
    const int bh = blockIdx.z;
    const int b  = bh / HH;
    const int h  = bh - b * HH;
    const int q0 = blockIdx.y * 128;
    const int n0 = blockIdx.x * 64;

    __shared__ alignas(16) unsigned short Ah[8 * 2 * 64 * 8];  // 16 KB
    __shared__ alignas(16) unsigned short Al[8 * 2 * 64 * 8];  // 16 KB
    __shared__ alignas(16) unsigned short Bh[4 * 2 * 64 * 8];  //  8 KB
    __shared__ alignas(16) unsigned short Bl[4 * 2 * 64 * 8];  //  8 KB

    const int tid  = threadIdx.x;
    const int lane = tid & 63;
    const int w    = tid >> 6;
    const int wm   = w & 1;
    const int wn   = w >> 1;

    // ---- stage A: 1024 16B chunks (m 0..127, c8 0..7), coalesced copy ----
    #pragma unroll
    for (int i = 0; i < 4; ++i) {
        const int c = tid + (i << 8);
        const int m = c >> 3, c8 = c & 7;
        const int qq = c8 >> 2, g = c8 & 3;
        const int slot = (((m >> 4) * 2 + qq) * 64 + (m & 15) + (g << 4)) * 8;
        const size_t o = (size_t)(b * LL + q0 + m) * DD + h * DKK + c8 * 8;
        *reinterpret_cast<u16x8*>(Ah + slot) = *reinterpret_cast<const u16x8*>(Qh + o);
        *reinterpret_cast<u16x8*>(Al + slot) = *reinterpret_cast<const u16x8*>(Ql + o);
    }
    // ---- stage B: 512 chunks (n 0..63, c8 0..7) ----
    #pragma unroll
    for (int i = 0; i < 2; ++i) {
        const int c = tid + (i << 8);
        const int n = c >> 3, c8 = c & 7;
        const int qq = c8 >> 2, g = c8 & 3;
        const int slot = (((n >> 4) * 2 + qq) * 64 + (n & 15) + (g << 4)) * 8;
        const size_t o = (size_t)(b * LL + n0 + n) * DD + h * DKK + c8 * 8;
        *reinterpret_cast<u16x8*>(Bh + slot) = *reinterpret_cast<const u16x8*>(Kh + o);
        *reinterpret_cast<u16x8*>(Bl + slot) = *reinterpret_cast<const u16x8*>(Kl + o);
    }
    __syncthreads();

    f32x4 acc[4][2] = {};
    #pragma unroll
    for (int qq = 0; qq < 2; ++qq) {
        bf16x8 aH[4], aL[4], bH[2], bL[2];
        #pragma unroll
        for (int fm = 0; fm < 4; ++fm) {
            const int f = (wm * 4 + fm) * 2 + qq;
            aH[fm] = *reinterpret_cast<const bf16x8*>(Ah + (f * 64 + lane) * 8);
            aL[fm] = *reinterpret_cast<const bf16x8*>(Al + (f * 64 + lane) * 8);
        }
        #pragma unroll
        for (int fn = 0; fn < 2; ++fn) {
            const int f = (wn * 2 + fn) * 2 + qq;
            bH[fn] = *reinterpret_cast<const bf16x8*>(Bh + (f * 64 + lane) * 8);
            bL[fn] = *reinterpret_cast<const bf16x8*>(Bl + (f * 64 + lane) * 8);
        }
        #pragma unroll
        for (int fm = 0; fm < 4; ++fm)
            #pragma unroll
            for (int fn = 0; fn < 2; ++fn) {
                acc[fm][fn] = __builtin_amdgcn_mfma_f32_16x16x32_bf16(aH[fm], bH[fn], acc[fm][fn], 0, 0, 0);
                acc[fm][fn] = __builtin_amdgcn_mfma_f32_16x16x32_bf16(aH[fm], bL[fn], acc[fm][fn], 0, 0, 0);
                acc[fm][fn] = __builtin_amdgcn_mfma_f32_16x16x32_bf16(aL[fm], bH[fn], acc[fm][fn], 0, 0, 0);
            }
    }

    // ---- epilogue: scale 1/16, mask, store f32 ----
    const int r0 = (lane >> 4) << 2;
    const int cl = lane & 15;
    #pragma unroll
    for (int fn = 0; fn < 2; ++fn) {
        const int col = n0 + wn * 32 + fn * 16 + cl;
        const int mk  = mask[b * LL + col];
        #pragma unroll
        for (int fm = 0; fm < 4; ++fm) {
            const int row = q0 + wm * 64 + fm * 16 + r0;
            const size_t base = ((size_t)bh * LL + row) * LL + col;
            #pragma unroll
            for (int r = 0; r < 4; ++r) {
                const float v = acc[fm][fn][r] * 0.0625f;   // (qk/8)/2
                S[base + (size_t)r * LL] = mk ? v : ZNEG;
            }
        }
    }
}

// ---------------------------------------------------------------------------
// Kernel 3: entmax-1.5, wave-per-head; 8 bisections + closed-form finish.
// tau* is the unique root of f(tau) = sum max(z-tau,0)^2 = 1, tau* in [-1,0].
// After 8 bisections (gap 2^-8), solve the single-quadratic piece exactly on
// the over-inclusive active set A = {z > lo}  (A contains the true support
// since lo <= tau*):  c*tau^2 - 2*s1*tau + (s2-1) = 0, left root.
// Over-inclusion error <= N_b*gap^2/2 (borderline elements contribute
// (z-tau*)^2 <= gap^2 each) -> tau err ~1e-5 typical, <=1.5e-4 pathological.
// ---------------------------------------------------------------------------
__device__ __forceinline__ float waveReduceSum(float v) {
    #pragma unroll
    for (int off = 32; off > 0; off >>= 1) v += __shfl_xor(v, off, 64);
    return v;
}
__device__ __forceinline__ float waveReduceMax(float v) {
    #pragma unroll
    for (int off = 32; off > 0; off >>= 1) v = fmaxf(v, __shfl_xor(v, off, 64));
    return v;
}

__global__ __launch_bounds__(256) void entmax_sum(
    const float* __restrict__ S, float* __restrict__ out)
{
    const int bq = blockIdx.x;          // b*LL + q
    const int b  = bq / LL;
    const int q  = bq - b * LL;
    const int tid = threadIdx.x;
    const int w  = tid >> 6;            // wave 0..3
    const int l  = tid & 63;            // lane 0..63

    __shared__ float buf[4][LL];        // per-wave head-partials, 24 KB

    float acc[24];
    #pragma unroll
    for (int i = 0; i < 24; ++i) acc[i] = 0.0f;

    #pragma unroll
    for (int hh = 0; hh < 3; ++hh) {
        const int h = w + (hh << 2);
        const float* row = S + ((size_t)(b * HH + h) * LL + q) * LL + l * 24;

        float z[24];
        #pragma unroll
        for (int i = 0; i < 24; i += 4) {
            float4 v = *reinterpret_cast<const float4*>(row + i);
            z[i] = v.x; z[i + 1] = v.y; z[i + 2] = v.z; z[i + 3] = v.w;
        }

        // ---- wave max + shift ----
        float m = z[0];
        #pragma unroll
        for (int i = 1; i < 24; ++i) m = fmaxf(m, z[i]);
        m = waveReduceMax(m);
        #pragma unroll
        for (int i = 0; i < 24; ++i) z[i] -= m;

        // ---- 8 bisection steps: tau in [-1, 0], bracket -> 2^-8 ----
        float lo = -1.0f, hi_ = 0.0f;
        #pragma unroll
        for (int it = 0; it < 8; ++it) {
            const float tau = 0.5f * (lo + hi_);
            float s = 0.0f;
            #pragma unroll
            for (int i = 0; i < 24; ++i) {
                const float t = fmaxf(z[i] - tau, 0.0f);
                s = fmaf(t, t, s);
            }
            s = waveReduceSum(s);
            if (s >= 1.0f) lo = tau; else hi_ = tau;
        }

        // ---- closed-form quadratic finish on A = {z > lo} ----
        float s1 = 0.0f, s2 = 0.0f, cn = 0.0f;
        #pragma unroll
        for (int i = 0; i < 24; ++i) {
            const bool a = z[i] > lo;
            const float t = a ? z[i] : 0.0f;
            s1 += t;
            s2 = fmaf(t, t, s2);
            cn += a ? 1.0f : 0.0f;
        }
        s1 = waveReduceSum(s1);
        s2 = waveReduceSum(s2);
        cn = waveReduceSum(cn);
        const float disc = fmaxf(fmaf(s1, s1, -cn * (s2 - 1.0f)), 0.0f);
        const float tau = (s1 - sqrtf(disc)) / cn;   // cn >= 1 (max elem z=0 > lo)

        #pragma unroll
        for (int i = 0; i < 24; ++i) {
            const float t = fmaxf(z[i] - tau, 0.0f);
            acc[i] = fmaf(t, t, acc[i]);
        }
    }

    // ---- join the 4 waves' head-partials ----
    #pragma unroll
    for (int i = 0; i < 24; ++i) buf[w][l * 24 + i] = acc[i];
    __syncthreads();

    float* orow = out + (size_t)bq * LL;
    #pragma unroll
    for (int i = 0; i < 6; ++i) {
        const int c = tid + (i << 8);
        orow[c] = (buf[0][c] + buf[1][c] + buf[2][c] + buf[3][c]) * (1.0f / 12.0f);
    }
}

// ---------------------------------------------------------------------------
extern "C" void kernel_launch(void* const* d_in, const int* in_sizes, int n_in,
                              void* d_out, int out_size, void* d_ws, size_t ws_size,
                              hipStream_t stream) {
    (void)in_sizes; (void)n_in; (void)out_size; (void)ws_size;
    const float* query = (const float*)d_in[0];
    const float* key   = (const float*)d_in[1];
    const int*   mask  = (const int*)d_in[2];
    const float* wq_w  = (const float*)d_in[3];
    const float* wq_b  = (const float*)d_in[4];
    const float* wk_w  = (const float*)d_in[5];
    const float* wk_b  = (const float*)d_in[6];
    float* out = (float*)d_out;

    const size_t NE = (size_t)BB * LL * DD;         // 2359296 elems
    unsigned short* Qh = (unsigned short*)d_ws;     // 4.7 MB each
    unsigned short* Ql = Qh + NE;
    unsigned short* Kh = Ql + NE;
    unsigned short* Kl = Kh + NE;
    float* S = (float*)(Kl + NE);                   // [B,H,L,L] 226.5 MB

    // K1: projections -> pre-split bf16 hi/lo (z dim: 0 = Q, 1 = K)
    proj_mfma<<<dim3(DD / 64, (BB * LL) / 128, 2), 256, 0, stream>>>(
        query, key, wq_w, wk_w, wq_b, wk_b, Qh, Ql, Kh, Kl);

    // K2: masked, pre-scaled scores (coalesced copy staging, no conversion)
    scores_mfma<<<dim3(LL / 64, LL / 128, BB * HH), 256, 0, stream>>>(
        Qh, Ql, Kh, Kl, mask, S);

    // K3: entmax + head average (8 bisections + closed-form finish)
    entmax_sum<<<BB * LL, 256, 0, stream>>>(S, out);
}